// Round 8
// baseline (1059.138 us; speedup 1.0000x reference)
//
#include <hip/hip_runtime.h>
#include <stdint.h>

#define NTOK 16384   // B*S = 4*4096
#define DIN 512
#define DOUT 512
#define KE 8
#define BM 128
#define BN 128
#define BK 64

#define GATE_BLOCKS 2048           // 8 tokens/block
#define WCONV_BLOCKS 1024          // 2M elements / (256*8)

typedef unsigned short u16;
typedef u16 u16x8 __attribute__((ext_vector_type(8)));
typedef __bf16 bf16x8 __attribute__((ext_vector_type(8)));
typedef float f32x4 __attribute__((ext_vector_type(4)));

__device__ __forceinline__ u16 f2bf(float f) {
  union { float f; unsigned u; } v; v.f = f;
  unsigned r = v.u + 0x7FFFu + ((v.u >> 16) & 1u);   // RNE; inputs are finite
  return (u16)(r >> 16);
}

// async global->LDS, 16B per lane; LDS dest is wave-uniform base + lane*16
#define GLOAD_LDS16(gp, lp)                                              \
  __builtin_amdgcn_global_load_lds(                                     \
      (__attribute__((address_space(1))) void*)(gp),                    \
      (__attribute__((address_space(3))) void*)(lp), 16, 0, 0)

// ---------------------------------------------------------------------------
// Kernel 1 (merged prologue):
//  blocks [0, GATE_BLOCKS): gating softmax + x fp32->bf16 cast (8 tok/block)
//  blocks [GATE_BLOCKS, +WCONV_BLOCKS): expert-weight fp32->bf16 cast
// Coeffs written TRANSPOSED: coeffsT[e][tok].
// ---------------------------------------------------------------------------
__global__ __launch_bounds__(256) void prologue_kernel(
    const float* __restrict__ x, const float* __restrict__ mw,
    const float* __restrict__ mb, const float* __restrict__ ew,
    u16* __restrict__ xbf, u16* __restrict__ wbf, float* __restrict__ coeffsT) {
  const int tid = threadIdx.x;

  if (blockIdx.x >= GATE_BLOCKS) {
    // ---- weight cast: 8 elements/thread ----
    const size_t i =
        ((size_t)(blockIdx.x - GATE_BLOCKS) * 256 + tid) * 8;
    const float4 a = *(const float4*)&ew[i];
    const float4 b = *(const float4*)&ew[i + 4];
    u16x8 p;
    p[0] = f2bf(a.x); p[1] = f2bf(a.y); p[2] = f2bf(a.z); p[3] = f2bf(a.w);
    p[4] = f2bf(b.x); p[5] = f2bf(b.y); p[6] = f2bf(b.z); p[7] = f2bf(b.w);
    *(u16x8*)&wbf[i] = p;
    return;
  }

  // ---- gating + x cast ----
  __shared__ __align__(16) float mwS[KE * DIN];   // 16 KB
  const int wave = tid >> 6, lane = tid & 63;

#pragma unroll
  for (int i = 0; i < 4; ++i) {
    const int idx = (tid + i * 256) * 4;
    *(float4*)&mwS[idx] = *(const float4*)&mw[idx];
  }
  float mbr[KE];
#pragma unroll
  for (int k = 0; k < KE; ++k) mbr[k] = mb[k];
  __syncthreads();

#pragma unroll
  for (int t = 0; t < 2; ++t) {
    const int tok = blockIdx.x * 8 + wave * 2 + t;
    const float* xr = x + (size_t)tok * DIN + lane * 8;
    const float4 xa = *(const float4*)xr;
    const float4 xb = *(const float4*)(xr + 4);

    u16x8 p;
    p[0] = f2bf(xa.x); p[1] = f2bf(xa.y); p[2] = f2bf(xa.z); p[3] = f2bf(xa.w);
    p[4] = f2bf(xb.x); p[5] = f2bf(xb.y); p[6] = f2bf(xb.z); p[7] = f2bf(xb.w);
    *(u16x8*)(xbf + (size_t)tok * DIN + lane * 8) = p;

    float lg[KE];
#pragma unroll
    for (int k = 0; k < KE; ++k) {
      const float* wr = &mwS[k * DIN + lane * 8];
      const float4 w0 = *(const float4*)wr;
      const float4 w1 = *(const float4*)(wr + 4);
      lg[k] = xa.x * w0.x + xa.y * w0.y + xa.z * w0.z + xa.w * w0.w +
              xb.x * w1.x + xb.y * w1.y + xb.z * w1.z + xb.w * w1.w;
    }
#pragma unroll
    for (int off = 32; off; off >>= 1)
#pragma unroll
      for (int k = 0; k < KE; ++k) lg[k] += __shfl_xor(lg[k], off);

#pragma unroll
    for (int k = 0; k < KE; ++k) lg[k] += mbr[k];
    float mx = lg[0];
#pragma unroll
    for (int k = 1; k < KE; ++k) mx = fmaxf(mx, lg[k]);
    float s = 0.f;
#pragma unroll
    for (int k = 0; k < KE; ++k) { lg[k] = __expf(lg[k] - mx); s += lg[k]; }
    const float inv = 1.f / s;
    if (lane == 0) {
#pragma unroll
      for (int k = 0; k < KE; ++k) coeffsT[(size_t)k * NTOK + tok] = lg[k] * inv;
    }
  }
}

// ---------------------------------------------------------------------------
// Kernel 2: main MoE GEMM. DS-traffic-optimized (R6 lesson: the limiter is
// DS-pipe + L2->LDS bytes, ~16 TB/s staged regardless of barrier grouping):
//   BM=BN=128, 256 threads (4 waves x 64x64 wave-tile = 4x4 frags),
//   t(K-tile) OUTER / expert INNER; A-frags af[4][2] (32 VGPRs) held in
//   registers across the e-loop -> A staged+frag-read once per t, not 8x.
//   Staged bytes 1.57 GB -> 0.58 GB; DS reads 3.2 GB -> 1.1 GB.
// Register budget (R3/R7 spill postmortem): acc 64 + part 64 + af 32 +
//   bfv 16 + addr ~25 = ~200 < 256 cap of __launch_bounds__(256,2).
//   part zero-init via C=0 operand on first-ks MFMA (no mov burst).
// - B double-buffered (2x16 KB); next tile staged before this tile's MFMAs.
// - XCD swizzle: XCD b&7 owns 16 contiguous m-blocks (A 2 MB L2-resident).
// - XOR-swizzled LDS (R4-R6 verified conflict-free): slot s of row r holds
//   global chunk s^(r&7).
// ---------------------------------------------------------------------------
__global__ __launch_bounds__(256, 2) void moe_gemm_kernel(
    const u16* __restrict__ xbf, const u16* __restrict__ wbf,
    const float* __restrict__ coeffsT, const float* __restrict__ ebias,
    float* __restrict__ out) {
  __shared__ __align__(16) u16 As[BM * BK];      // 16 KB (single; af held in regs)
  __shared__ __align__(16) u16 Bs[2][BN * BK];   // 2 x 16 KB
  __shared__ __align__(16) float CsT[KE * BM];   // 4 KB [e][row]
  __shared__ __align__(16) float BiS[KE * BN];   // 4 KB [e][col]

  const int tid = threadIdx.x;
  const int wave = tid >> 6, lane = tid & 63;

  // XCD swizzle: b&7 = xcd, s = intra-XCD sequence (64 blocks/XCD).
  const int b = blockIdx.x;
  const int xcd = b & 7, s = b >> 3;
  const int m0 = (xcd * 16 + (s & 15)) * BM;
  const int n0 = (s >> 4) * BN;

  const int wm = (wave >> 1) * 64;   // wave row offset: {0,64}
  const int wn = (wave & 1) * 64;    // wave col offset: {0,64}

  // stage coeffs [e][row] and bias [e][col] (fp32, 4 KB each): float4/thread
  {
    const int e = tid >> 5, c = (tid & 31) * 4;
    *(float4*)&CsT[e * BM + c] =
        *(const float4*)&coeffsT[(size_t)e * NTOK + m0 + c];
    *(float4*)&BiS[e * BN + c] = *(const float4*)&ebias[e * DOUT + n0 + c];
  }

  // staging: 16 chunks of 1 KB per tile (8 rows x 64 cols), 4 chunks/wave.
  // lane -> row lrow; SOURCE col chunk XOR-swizzled: LDS slot s of row r
  // holds global chunk s^(r&7).
  const int lrow = lane >> 3;
  const int scol = ((lane & 7) ^ lrow) * 8;
  const u16* aBase = xbf + (size_t)(m0 + wave * 32 + lrow) * DIN + scol;
  const u16* bBase = wbf + (size_t)(n0 + wave * 32 + lrow) * DIN + scol;

#define STAGE_A(T)                                                            \
  do {                                                                        \
    _Pragma("unroll")                                                         \
    for (int j = 0; j < 4; ++j)                                               \
      GLOAD_LDS16(aBase + (size_t)(j * 8) * DIN + (T) * 64,                   \
                  &As[(wave * 4 + j) * 512]);                                 \
  } while (0)

#define STAGE_B(E, T, BUF)                                                    \
  do {                                                                        \
    const u16* bb_ = bBase + (size_t)(E) * (DOUT * DIN) + (T) * 64;           \
    _Pragma("unroll")                                                         \
    for (int j = 0; j < 4; ++j)                                               \
      GLOAD_LDS16(bb_ + (size_t)(j * 8) * DIN,                                \
                  &Bs[BUF][(wave * 4 + j) * 512]);                            \
  } while (0)

  const int frow = lane & 15;
  const int fsel = lane >> 4;
  const int fxor = lane & 7;
  const int quad = lane >> 4;

  f32x4 acc[4][4] = {};
  const f32x4 zero4 = (f32x4)(0.f);

  STAGE_A(0);
  STAGE_B(0, 0, 0);
  __syncthreads();

  for (int t = 0; t < 8; ++t) {
    // A-fragments for this K-tile -> registers, held across the expert loop
    bf16x8 af[4][2];
#pragma unroll
    for (int ks = 0; ks < 2; ++ks) {
      const int slot = (ks * 4 + fsel) ^ fxor;
#pragma unroll
      for (int mi = 0; mi < 4; ++mi)
        af[mi][ks] = *(const bf16x8*)&As[(wm + mi * 16 + frow) * BK + slot * 8];
    }

    for (int e = 0; e < KE; ++e) {
      const int buf = e & 1;
      // stage next tile(s) before computing -> drain overlaps MFMAs.
      // As is safe to overwrite at e==7: af regs hold A(t), and every wave
      // consumed its ds_reads of As before its own e=0 MFMAs (pre-barrier).
      if (e < 7) {
        STAGE_B(e + 1, t, buf ^ 1);
      } else if (t < 7) {
        STAGE_A(t + 1);
        STAGE_B(0, t + 1, buf ^ 1);
      }

      f32x4 part[4][4];
#pragma unroll
      for (int ks = 0; ks < 2; ++ks) {
        const int slot = (ks * 4 + fsel) ^ fxor;
        bf16x8 bfv[4];
#pragma unroll
        for (int ni = 0; ni < 4; ++ni)
          bfv[ni] =
              *(const bf16x8*)&Bs[buf][(wn + ni * 16 + frow) * BK + slot * 8];
#pragma unroll
        for (int mi = 0; mi < 4; ++mi)
#pragma unroll
          for (int ni = 0; ni < 4; ++ni)
            part[mi][ni] = __builtin_amdgcn_mfma_f32_16x16x32_bf16(
                af[mi][ks], bfv[ni], ks == 0 ? zero4 : part[mi][ni], 0, 0, 0);
      }

      // fold: acc += c[row,e] * part (fp32 VALU; hides under MFMA pipe m114)
      // C/D layout (m89/m91): col = lane&15, row = quad*4 + reg
#pragma unroll
      for (int mi = 0; mi < 4; ++mi) {
        const float4 c4 = *(const float4*)&CsT[e * BM + wm + mi * 16 + quad * 4];
#pragma unroll
        for (int ni = 0; ni < 4; ++ni) {
          acc[mi][ni][0] += c4.x * part[mi][ni][0];
          acc[mi][ni][1] += c4.y * part[mi][ni][1];
          acc[mi][ni][2] += c4.z * part[mi][ni][2];
          acc[mi][ni][3] += c4.w * part[mi][ni][3];
        }
      }

      __syncthreads();   // Bs[buf] reads done; next stage drained
    }
  }

  // epilogue: rank-8 bias update from LDS + store
  float bcol[4][KE];
#pragma unroll
  for (int ni = 0; ni < 4; ++ni) {
    const int col = wn + ni * 16 + frow;
#pragma unroll
    for (int k = 0; k < KE; ++k) bcol[ni][k] = BiS[k * BN + col];
  }
#pragma unroll
  for (int mi = 0; mi < 4; ++mi) {
    const int rb = wm + mi * 16 + quad * 4;
#pragma unroll
    for (int j = 0; j < 4; ++j) {
      const int row = rb + j;
      float cr[KE];
#pragma unroll
      for (int k = 0; k < KE; ++k) cr[k] = CsT[k * BM + row];
#pragma unroll
      for (int ni = 0; ni < 4; ++ni) {
        float bias = 0.f;
#pragma unroll
        for (int k = 0; k < KE; ++k) bias += cr[k] * bcol[ni][k];
        const int col = wn + ni * 16 + frow;
        out[(size_t)(m0 + row) * DOUT + n0 + col] = acc[mi][ni][j] + bias;
      }
    }
  }
}

// ---------------------------------------------------------------------------
extern "C" void kernel_launch(void* const* d_in, const int* in_sizes, int n_in,
                              void* d_out, int out_size, void* d_ws,
                              size_t ws_size, hipStream_t stream) {
  (void)in_sizes; (void)n_in; (void)out_size; (void)ws_size;
  const float* x  = (const float*)d_in[0];   // [4,4096,512]
  const float* ew = (const float*)d_in[1];   // [8,512,512]
  const float* eb = (const float*)d_in[2];   // [8,512]
  const float* mw = (const float*)d_in[3];   // [8,512]
  const float* mb = (const float*)d_in[4];   // [8]
  float* out = (float*)d_out;                // [4,4096,512]

  // workspace layout: xbf 16 MB | wbf 4 MB | coeffsT 0.5 MB  (~20.5 MB)
  u16* xbf = (u16*)d_ws;
  u16* wbf = (u16*)((char*)d_ws + (size_t)NTOK * DIN * 2);
  float* coeffsT =
      (float*)((char*)d_ws + (size_t)NTOK * DIN * 2 + (size_t)KE * DOUT * DIN * 2);

  hipLaunchKernelGGL(prologue_kernel, dim3(GATE_BLOCKS + WCONV_BLOCKS),
                     dim3(256), 0, stream, x, mw, mb, ew, xbf, wbf, coeffsT);
  hipLaunchKernelGGL(moe_gemm_kernel, dim3((NTOK / BM) * (DOUT / BN)), dim3(256),
                     0, stream, xbf, wbf, coeffsT, eb, out);
}

// Round 9
// 235.648 us; speedup vs baseline: 4.4946x; 4.4946x over previous
//
#include <hip/hip_runtime.h>
#include <stdint.h>

#define NTOK 16384   // B*S = 4*4096
#define DIN 512
#define DOUT 512
#define KE 8
#define BM 128
#define BN 128
#define BK 64

#define GATE_BLOCKS 2048           // 8 tokens/block
#define WCONV_BLOCKS 1024          // 2M elements / (256*8)

typedef unsigned short u16;
typedef u16 u16x8 __attribute__((ext_vector_type(8)));
typedef __bf16 bf16x8 __attribute__((ext_vector_type(8)));
typedef float f32x4 __attribute__((ext_vector_type(4)));

__device__ __forceinline__ u16 f2bf(float f) {
  union { float f; unsigned u; } v; v.f = f;
  unsigned r = v.u + 0x7FFFu + ((v.u >> 16) & 1u);   // RNE; inputs are finite
  return (u16)(r >> 16);
}

// async global->LDS, 16B per lane; LDS dest is wave-uniform base + lane*16
#define GLOAD_LDS16(gp, lp)                                              \
  __builtin_amdgcn_global_load_lds(                                     \
      (__attribute__((address_space(1))) void*)(gp),                    \
      (__attribute__((address_space(3))) void*)(lp), 16, 0, 0)

// ---------------------------------------------------------------------------
// Kernel 1 (merged prologue):
//  blocks [0, GATE_BLOCKS): gating softmax + x fp32->bf16 cast (8 tok/block)
//  blocks [GATE_BLOCKS, +WCONV_BLOCKS): expert-weight fp32->bf16 cast
// Coeffs written TRANSPOSED: coeffsT[e][tok].
// ---------------------------------------------------------------------------
__global__ __launch_bounds__(256) void prologue_kernel(
    const float* __restrict__ x, const float* __restrict__ mw,
    const float* __restrict__ mb, const float* __restrict__ ew,
    u16* __restrict__ xbf, u16* __restrict__ wbf, float* __restrict__ coeffsT) {
  const int tid = threadIdx.x;

  if (blockIdx.x >= GATE_BLOCKS) {
    // ---- weight cast: 8 elements/thread ----
    const size_t i =
        ((size_t)(blockIdx.x - GATE_BLOCKS) * 256 + tid) * 8;
    const float4 a = *(const float4*)&ew[i];
    const float4 b = *(const float4*)&ew[i + 4];
    u16x8 p;
    p[0] = f2bf(a.x); p[1] = f2bf(a.y); p[2] = f2bf(a.z); p[3] = f2bf(a.w);
    p[4] = f2bf(b.x); p[5] = f2bf(b.y); p[6] = f2bf(b.z); p[7] = f2bf(b.w);
    *(u16x8*)&wbf[i] = p;
    return;
  }

  // ---- gating + x cast ----
  __shared__ __align__(16) float mwS[KE * DIN];   // 16 KB
  const int wave = tid >> 6, lane = tid & 63;

#pragma unroll
  for (int i = 0; i < 4; ++i) {
    const int idx = (tid + i * 256) * 4;
    *(float4*)&mwS[idx] = *(const float4*)&mw[idx];
  }
  float mbr[KE];
#pragma unroll
  for (int k = 0; k < KE; ++k) mbr[k] = mb[k];
  __syncthreads();

#pragma unroll
  for (int t = 0; t < 2; ++t) {
    const int tok = blockIdx.x * 8 + wave * 2 + t;
    const float* xr = x + (size_t)tok * DIN + lane * 8;
    const float4 xa = *(const float4*)xr;
    const float4 xb = *(const float4*)(xr + 4);

    u16x8 p;
    p[0] = f2bf(xa.x); p[1] = f2bf(xa.y); p[2] = f2bf(xa.z); p[3] = f2bf(xa.w);
    p[4] = f2bf(xb.x); p[5] = f2bf(xb.y); p[6] = f2bf(xb.z); p[7] = f2bf(xb.w);
    *(u16x8*)(xbf + (size_t)tok * DIN + lane * 8) = p;

    float lg[KE];
#pragma unroll
    for (int k = 0; k < KE; ++k) {
      const float* wr = &mwS[k * DIN + lane * 8];
      const float4 w0 = *(const float4*)wr;
      const float4 w1 = *(const float4*)(wr + 4);
      lg[k] = xa.x * w0.x + xa.y * w0.y + xa.z * w0.z + xa.w * w0.w +
              xb.x * w1.x + xb.y * w1.y + xb.z * w1.z + xb.w * w1.w;
    }
#pragma unroll
    for (int off = 32; off; off >>= 1)
#pragma unroll
      for (int k = 0; k < KE; ++k) lg[k] += __shfl_xor(lg[k], off);

#pragma unroll
    for (int k = 0; k < KE; ++k) lg[k] += mbr[k];
    float mx = lg[0];
#pragma unroll
    for (int k = 1; k < KE; ++k) mx = fmaxf(mx, lg[k]);
    float s = 0.f;
#pragma unroll
    for (int k = 0; k < KE; ++k) { lg[k] = __expf(lg[k] - mx); s += lg[k]; }
    const float inv = 1.f / s;
    if (lane == 0) {
#pragma unroll
      for (int k = 0; k < KE; ++k) coeffsT[(size_t)k * NTOK + tok] = lg[k] * inv;
    }
  }
}

// ---------------------------------------------------------------------------
// Kernel 2: main MoE GEMM.
// Staged-bytes-optimized WITHOUT the register-heavy wave-tile (R3/R7/R8
// lesson: two 4x4 f32x4 accumulator sets ALWAYS spill; 32x64 wave-tile with
// acc+part 2x(2x4) is the only proven no-spill shape, VGPR 64-80).
//   BM=BN=128, 512 threads = 8 waves x 32x64 wave-tile.
//   t(K-tile) OUTER / expert INNER: A(t) staged to LDS ONCE per t (not 8x);
//   per-expert A-fragments re-read from LDS (2 ds_read_b128/wave -- cheap).
//   Staged L2->LDS traffic: R6 1.6 GB -> 604 MB (B 537 + A 67), vs the
//   ~27 B/cyc/CU global_load_lds path ceiling => ~36 us floor, ~= MFMA floor.
// - A and B double-buffered (A(t+1) staged at e==7 into As[buf^1]).
// - XCD swizzle: XCD b&7 owns 16 contiguous m-blocks.
// - XOR-swizzled LDS (verified conflict-free R4-R8): slot s of row r holds
//   global chunk s^(r&7).
// LDS 72 KB -> 2 blocks/CU (16 waves). __launch_bounds__(512,4) caps 128
// VGPR; demand ~80 (R6-measured for same wave body).
// ---------------------------------------------------------------------------
__global__ __launch_bounds__(512, 4) void moe_gemm_kernel(
    const u16* __restrict__ xbf, const u16* __restrict__ wbf,
    const float* __restrict__ coeffsT, const float* __restrict__ ebias,
    float* __restrict__ out) {
  __shared__ __align__(16) u16 As[2][BM * BK];   // 2 x 16 KB
  __shared__ __align__(16) u16 Bs[2][BN * BK];   // 2 x 16 KB
  __shared__ __align__(16) float CsT[KE * BM];   // 4 KB [e][row]
  __shared__ __align__(16) float BiS[KE * BN];   // 4 KB [e][col]

  const int tid = threadIdx.x;
  const int wave = tid >> 6, lane = tid & 63;

  // XCD swizzle: b&7 = xcd, s = intra-XCD sequence (64 blocks/XCD).
  const int b = blockIdx.x;
  const int xcd = b & 7, s = b >> 3;
  const int m0 = (xcd * 16 + (s & 15)) * BM;
  const int n0 = (s >> 4) * BN;

  const int wm = (wave & 3) * 32;    // wave row offset: 0,32,64,96
  const int wn = (wave >> 2) * 64;   // wave col offset: 0,64

  // stage coeffs [e][row] and bias [e][col] (fp32, 4 KB each)
  if (tid < 256) {
    const int e = tid >> 5, c = (tid & 31) * 4;
    *(float4*)&CsT[e * BM + c] =
        *(const float4*)&coeffsT[(size_t)e * NTOK + m0 + c];
  } else {
    const int t2 = tid - 256;
    const int e = t2 >> 5, c = (t2 & 31) * 4;
    *(float4*)&BiS[e * BN + c] = *(const float4*)&ebias[e * DOUT + n0 + c];
  }

  // staging: tile = 128 rows x 64 cols = 16 chunks of 1 KB (8 rows each);
  // 2 chunks/wave. lane -> row lrow; SOURCE col chunk XOR-swizzled:
  // LDS slot s of row r holds global chunk s^(r&7).
  const int lrow = lane >> 3;
  const int scol = ((lane & 7) ^ lrow) * 8;
  const u16* aBase = xbf + (size_t)(m0 + wave * 16 + lrow) * DIN + scol;
  const u16* bBase = wbf + (size_t)(n0 + wave * 16 + lrow) * DIN + scol;

#define STAGE_A(T, BUF)                                                       \
  do {                                                                        \
    _Pragma("unroll")                                                         \
    for (int j = 0; j < 2; ++j)                                               \
      GLOAD_LDS16(aBase + (size_t)(j * 8) * DIN + (T) * 64,                   \
                  &As[BUF][(wave * 2 + j) * 512]);                            \
  } while (0)

#define STAGE_B(E, T, BUF)                                                    \
  do {                                                                        \
    const u16* bb_ = bBase + (size_t)(E) * (DOUT * DIN) + (T) * 64;           \
    _Pragma("unroll")                                                         \
    for (int j = 0; j < 2; ++j)                                               \
      GLOAD_LDS16(bb_ + (size_t)(j * 8) * DIN,                                \
                  &Bs[BUF][(wave * 2 + j) * 512]);                            \
  } while (0)

  const int frow = lane & 15;
  const int fsel = lane >> 4;
  const int fxor = lane & 7;
  const int quad = lane >> 4;

  f32x4 acc[2][4] = {};
  const f32x4 zero4 = (f32x4)(0.f);

  STAGE_A(0, 0);
  STAGE_B(0, 0, 0);
  __syncthreads();

  for (int t = 0; t < 8; ++t) {
    const int abuf = t & 1;

    for (int e = 0; e < KE; ++e) {
      const int buf = e & 1;
      // stage next tile(s) first -> drain overlaps this iteration's MFMAs
      if (e < 7) {
        STAGE_B(e + 1, t, buf ^ 1);
      } else if (t < 7) {
        STAGE_A(t + 1, abuf ^ 1);
        STAGE_B(0, t + 1, buf ^ 1);
      }

      f32x4 part[2][4];
#pragma unroll
      for (int ks = 0; ks < 2; ++ks) {
        const int slot = (ks * 4 + fsel) ^ fxor;
        bf16x8 af[2], bfv[4];
#pragma unroll
        for (int mi = 0; mi < 2; ++mi)
          af[mi] =
              *(const bf16x8*)&As[abuf][(wm + mi * 16 + frow) * BK + slot * 8];
#pragma unroll
        for (int ni = 0; ni < 4; ++ni)
          bfv[ni] =
              *(const bf16x8*)&Bs[buf][(wn + ni * 16 + frow) * BK + slot * 8];
#pragma unroll
        for (int mi = 0; mi < 2; ++mi)
#pragma unroll
          for (int ni = 0; ni < 4; ++ni)
            part[mi][ni] = __builtin_amdgcn_mfma_f32_16x16x32_bf16(
                af[mi], bfv[ni], ks == 0 ? zero4 : part[mi][ni], 0, 0, 0);
      }

      // fold: acc += c[row,e] * part (fp32 VALU, co-issues with MFMA m114)
      // C/D layout (m89/m91): col = lane&15, row = quad*4 + reg
#pragma unroll
      for (int mi = 0; mi < 2; ++mi) {
        const float4 c4 = *(const float4*)&CsT[e * BM + wm + mi * 16 + quad * 4];
#pragma unroll
        for (int ni = 0; ni < 4; ++ni) {
          acc[mi][ni][0] += c4.x * part[mi][ni][0];
          acc[mi][ni][1] += c4.y * part[mi][ni][1];
          acc[mi][ni][2] += c4.z * part[mi][ni][2];
          acc[mi][ni][3] += c4.w * part[mi][ni][3];
        }
      }

      __syncthreads();   // LDS reads done; staged loads drained
    }
  }

  // epilogue: rank-8 bias update from LDS + store
  float bcol[4][KE];
#pragma unroll
  for (int ni = 0; ni < 4; ++ni) {
    const int col = wn + ni * 16 + frow;
#pragma unroll
    for (int k = 0; k < KE; ++k) bcol[ni][k] = BiS[k * BN + col];
  }
#pragma unroll
  for (int mi = 0; mi < 2; ++mi) {
    const int rb = wm + mi * 16 + quad * 4;
#pragma unroll
    for (int j = 0; j < 4; ++j) {
      const int row = rb + j;
      float cr[KE];
#pragma unroll
      for (int k = 0; k < KE; ++k) cr[k] = CsT[k * BM + row];
#pragma unroll
      for (int ni = 0; ni < 4; ++ni) {
        float bias = 0.f;
#pragma unroll
        for (int k = 0; k < KE; ++k) bias += cr[k] * bcol[ni][k];
        const int col = wn + ni * 16 + frow;
        out[(size_t)(m0 + row) * DOUT + n0 + col] = acc[mi][ni][j] + bias;
      }
    }
  }
}

// ---------------------------------------------------------------------------
extern "C" void kernel_launch(void* const* d_in, const int* in_sizes, int n_in,
                              void* d_out, int out_size, void* d_ws,
                              size_t ws_size, hipStream_t stream) {
  (void)in_sizes; (void)n_in; (void)out_size; (void)ws_size;
  const float* x  = (const float*)d_in[0];   // [4,4096,512]
  const float* ew = (const float*)d_in[1];   // [8,512,512]
  const float* eb = (const float*)d_in[2];   // [8,512]
  const float* mw = (const float*)d_in[3];   // [8,512]
  const float* mb = (const float*)d_in[4];   // [8]
  float* out = (float*)d_out;                // [4,4096,512]

  // workspace layout: xbf 16 MB | wbf 4 MB | coeffsT 0.5 MB  (~20.5 MB)
  u16* xbf = (u16*)d_ws;
  u16* wbf = (u16*)((char*)d_ws + (size_t)NTOK * DIN * 2);
  float* coeffsT =
      (float*)((char*)d_ws + (size_t)NTOK * DIN * 2 + (size_t)KE * DOUT * DIN * 2);

  hipLaunchKernelGGL(prologue_kernel, dim3(GATE_BLOCKS + WCONV_BLOCKS),
                     dim3(256), 0, stream, x, mw, mb, ew, xbf, wbf, coeffsT);
  hipLaunchKernelGGL(moe_gemm_kernel, dim3((NTOK / BM) * (DOUT / BN)), dim3(512),
                     0, stream, xbf, wbf, coeffsT, eb, out);
}